// Round 11
// baseline (1463.090 us; speedup 1.0000x reference)
//
#include <hip/hip_runtime.h>
#include <hip/hip_fp16.h>

// ---------------------------------------------------------------------------
// GCN (3 layers) + global mean pool + linear, fp32 in/out, MI355X.
// norm = dinv[src]*dinv[dst] factors -> fold dinv into matmul output
// (t'[i] = dinv[i] * h[i] W^T); aggregation is a pure unweighted sum:
//   h_next[i] = relu(dinv[i]*(t'[i] + sum_{j->i} t'[j]) + b)
// R3-R5 (counter-verified): scattered 4B GLOBAL stores/atomics cost a ~32B
//   HBM sector each regardless of L2 residency; dense stores only.
// R9: fp16 t -> row = 128B = 1 L2 line; absmax 1.2e-4 passes.
// R11: CSR ELIMINATED. 1024 dst-buckets (<=49 nodes); agg = block-per-bucket
//   LDS-scatter: stream (src,dst) recs, gather t[src] (8 grp x 8 lane x 16B),
//   ds_add_f32 into 12.5KB LDS accumulator (LDS scatter is cheap -- only
//   global scatter pays sectors), dense 256B row epilogue. Deletes
//   sortfill/scan/csr/rp; dinv from a per-bucket histogram. 10 launches.
// ---------------------------------------------------------------------------

#define NBK 1024
#define CAPB 1536   // bucket capacity; mean 1221, sigma 35 -> 9 sigma slack
#define BINTILE 4096
#define MAXNN 49    // max nodes per bucket = ceil(50000/1024)

__global__ __launch_bounds__(256) void init_kernel(int* __restrict__ fctr) {
    int idx = blockIdx.x * blockDim.x + threadIdx.x;
    if (idx < NBK) fctr[idx] = 0;
}

// Bucket edges into 1024 dst-ranges (fixed capacity CAPB, base = g*CAPB).
// Per 4096-edge tile: dst+bucket cached in regs; sweep1 LDS histogram; one
// global reservation per bucket; sweep2 dense ~4-rec (32B = 1 sector) runs.
__global__ __launch_bounds__(256) void bin_kernel(const int* __restrict__ src,
                                                  const int* __restrict__ dst,
                                                  int* __restrict__ fctr,
                                                  int2* __restrict__ recs,
                                                  int e, int n) {
    __shared__ int lcnt[NBK], gbase[NBK];
    int tid = threadIdx.x;
    int s0  = blockIdx.x * BINTILE;
#pragma unroll
    for (int j = 0; j < 4; ++j) lcnt[tid + j * 256] = 0;
    __syncthreads();
    int dv[16], bk[16];
#pragma unroll
    for (int k = 0; k < 16; ++k) {
        int i = s0 + tid + k * 256;  // coalesced
        if (i < e) {
            dv[k] = dst[i];
            bk[k] = (int)(((long long)NBK * dv[k]) / n);
            atomicAdd(&lcnt[bk[k]], 1);
        } else {
            bk[k] = -1;
        }
    }
    __syncthreads();
#pragma unroll
    for (int j = 0; j < 4; ++j) {
        int b = tid + j * 256;
        gbase[b] = b * CAPB + atomicAdd(&fctr[b], lcnt[b]);
        lcnt[b]  = 0;  // reuse as placement counter
    }
    __syncthreads();
#pragma unroll
    for (int k = 0; k < 16; ++k) {
        if (bk[k] >= 0) {
            int i = s0 + tid + k * 256;
            int p = gbase[bk[k]] + atomicAdd(&lcnt[bk[k]], 1);
            if (p < (bk[k] + 1) * CAPB) recs[p] = make_int2(src[i], dv[k]);
        }
    }
}

// Per-bucket degree histogram -> dense dinv writes (<=49 floats per block).
__global__ __launch_bounds__(256) void dinv_kernel(const int2* __restrict__ recs,
                                                   const int* __restrict__ fctr,
                                                   float* __restrict__ dinv, int n) {
    __shared__ int hist[64];
    int g   = blockIdx.x;
    int N0  = (int)(((long long)n * g + NBK - 1) / NBK);
    int N1  = (int)(((long long)n * (g + 1) + NBK - 1) / NBK);
    int nn  = N1 - N0;  // <= 49
    int tid = threadIdx.x;
    if (tid < 64) hist[tid] = 0;
    __syncthreads();
    const int2* my = recs + (size_t)g * CAPB;
    int total = min(fctr[g], CAPB);
    for (int i = tid; i < total; i += 256)
        atomicAdd(&hist[my[i].y - N0], 1);
    __syncthreads();
    if (tid < nn) dinv[N0 + tid] = rsqrtf((float)(hist[tid] + 1));
}

// t[i][o] = fp16( dinv[i] * sum_k h[i][k] * W[o][k] )
// 256 thr = 4 waves; 64 nodes/block. W row per lane in 16 float4 regs;
// 64 h-rows staged in LDS, read as broadcast float4. Row store = dense 128B.
__global__ __launch_bounds__(256) void mm_kernel(const float* __restrict__ h,
                                                 const float* __restrict__ W,
                                                 const float* __restrict__ dinv,
                                                 __half* __restrict__ t, int n) {
    __shared__ float hs[64 * 64];
    int tid  = threadIdx.x;
    int lane = tid & 63;
    int wave = tid >> 6;
    int base = blockIdx.x * 64;

    float4 wreg[16];
    const float4* W4 = (const float4*)(W + lane * 64);
#pragma unroll
    for (int q = 0; q < 16; ++q) wreg[q] = W4[q];

    int nrows = min(64, n - base);
    const float4* h4  = (const float4*)(h + (size_t)base * 64);
    float4*       hs4 = (float4*)hs;
    for (int idx = tid; idx < nrows * 16; idx += 256) hs4[idx] = h4[idx];
    __syncthreads();

    for (int r = wave * 16; r < wave * 16 + 16; ++r) {
        int i = base + r;
        if (i >= n) break;
        const float4* row = (const float4*)(hs + r * 64);
        float acc = 0.0f;
#pragma unroll
        for (int q = 0; q < 16; ++q) {
            float4 hv = row[q];  // wave-uniform address -> LDS broadcast
            acc += hv.x * wreg[q].x + hv.y * wreg[q].y +
                   hv.z * wreg[q].z + hv.w * wreg[q].w;
        }
        t[(size_t)i * 64 + lane] = __float2half(acc * dinv[i]);
    }
}

static __device__ __forceinline__ void lds_acc8(float* a, uint4 u) {
    float2 f;
    f = __half22float2(*(const __half2*)&u.x);
    atomicAdd(&a[0], f.x); atomicAdd(&a[1], f.y);
    f = __half22float2(*(const __half2*)&u.y);
    atomicAdd(&a[2], f.x); atomicAdd(&a[3], f.y);
    f = __half22float2(*(const __half2*)&u.z);
    atomicAdd(&a[4], f.x); atomicAdd(&a[5], f.y);
    f = __half22float2(*(const __half2*)&u.w);
    atomicAdd(&a[6], f.x); atomicAdd(&a[7], f.y);
}

// LDS-scatter aggregation: one block per dst-bucket. Stream bucket records
// (coalesced), gather t[src] rows (8 edge-groups x 8 lanes x 16B = 1KB per
// vmem instr, 4-deep unroll), ds_add_f32 into the 49-row LDS accumulator.
// Epilogue: self + dinv scale + bias + relu -> dense 256B row stores.
__global__ __launch_bounds__(256) void agg_kernel(const int2* __restrict__ recs,
                                                  const int* __restrict__ fctr,
                                                  const __half* __restrict__ t,
                                                  const float* __restrict__ dinv,
                                                  const float* __restrict__ bias,
                                                  float* __restrict__ hout, int n) {
    __shared__ float acc[MAXNN * 64];
    int g   = blockIdx.x;
    int N0  = (int)(((long long)n * g + NBK - 1) / NBK);
    int N1  = (int)(((long long)n * (g + 1) + NBK - 1) / NBK);
    int nn  = N1 - N0;  // <= 49
    int tid = threadIdx.x;
    for (int idx = tid; idx < nn * 64; idx += 256) acc[idx] = 0.0f;
    __syncthreads();

    const int2* my = recs + (size_t)g * CAPB;
    int total = min(fctr[g], CAPB);
    int grp = tid >> 3;        // 32 edge-groups per block
    int fo  = (tid & 7) << 3;  // feature offset 0,8,..,56 (halves == floats)

    int e = grp;
    for (; e + 96 < total; e += 128) {
        int2 r0 = my[e];
        int2 r1 = my[e + 32];
        int2 r2 = my[e + 64];
        int2 r3 = my[e + 96];
        uint4 u0 = *(const uint4*)(t + (size_t)r0.x * 64 + fo);
        uint4 u1 = *(const uint4*)(t + (size_t)r1.x * 64 + fo);
        uint4 u2 = *(const uint4*)(t + (size_t)r2.x * 64 + fo);
        uint4 u3 = *(const uint4*)(t + (size_t)r3.x * 64 + fo);
        lds_acc8(acc + (r0.y - N0) * 64 + fo, u0);
        lds_acc8(acc + (r1.y - N0) * 64 + fo, u1);
        lds_acc8(acc + (r2.y - N0) * 64 + fo, u2);
        lds_acc8(acc + (r3.y - N0) * 64 + fo, u3);
    }
    for (; e < total; e += 32) {
        int2 r = my[e];
        uint4 u = *(const uint4*)(t + (size_t)r.x * 64 + fo);
        lds_acc8(acc + (r.y - N0) * 64 + fo, u);
    }
    __syncthreads();

    int wave = tid >> 6;
    int lane = tid & 63;
    for (int r = wave; r < nn; r += 4) {
        int i = N0 + r;
        float v = acc[r * 64 + lane] + __half2float(t[(size_t)i * 64 + lane]);
        hout[(size_t)i * 64 + lane] =
            fmaxf(fmaf(dinv[i], v, bias[lane]), 0.0f);
    }
}

// Fused mean-pool + linear: one block per graph. Node range via binary
// search in sorted batch (L2-hot); register accumulate (NO atomics);
// wave0 computes mean and the 16-wide output row.
__global__ __launch_bounds__(256) void poolfinal_kernel(const float* __restrict__ h,
                                                        const int* __restrict__ batch,
                                                        const float* __restrict__ Wl,
                                                        const float* __restrict__ bl,
                                                        float* __restrict__ out,
                                                        int n) {
    __shared__ float red[4][64];
    int b    = blockIdx.x;
    int tid  = threadIdx.x;
    int lane = tid & 63;
    int w    = tid >> 6;
    int l = 0, r = n;
    while (l < r) { int m = (l + r) >> 1; if (batch[m] < b) l = m + 1; else r = m; }
    int lo = l;
    r = n;
    while (l < r) { int m = (l + r) >> 1; if (batch[m] < b + 1) l = m + 1; else r = m; }
    int hi = l;

    float acc = 0.0f;
    for (int i = lo + w; i < hi; i += 4) acc += h[(size_t)i * 64 + lane];
    red[w][lane] = acc;
    __syncthreads();
    if (w == 0) {
        float s = (red[0][lane] + red[1][lane]) + (red[2][lane] + red[3][lane]);
        float c = (float)(hi - lo);
        red[0][lane] = s / fmaxf(c, 1.0f);
    }
    __syncthreads();
    if (tid < 16) {
        float a = bl[tid];
        const float* wr = Wl + tid * 64;
#pragma unroll
        for (int k = 0; k < 64; ++k) a += red[0][k] * wr[k];
        out[b * 16 + tid] = a;
    }
}

extern "C" void kernel_launch(void* const* d_in, const int* in_sizes, int n_in,
                              void* d_out, int out_size, void* d_ws, size_t ws_size,
                              hipStream_t stream) {
    const float* x    = (const float*)d_in[0];
    const int*   ei   = (const int*)d_in[1];
    const int*   batch= (const int*)d_in[2];
    const float* W1   = (const float*)d_in[3];
    const float* b1   = (const float*)d_in[4];
    const float* W2   = (const float*)d_in[5];
    const float* b2   = (const float*)d_in[6];
    const float* W3   = (const float*)d_in[7];
    const float* b3   = (const float*)d_in[8];
    const float* Wl   = (const float*)d_in[9];
    const float* bl   = (const float*)d_in[10];
    float* out = (float*)d_out;

    const int n  = in_sizes[0] / 64;   // 50000 nodes
    const int e  = in_sizes[1] / 2;    // 1250000 edges
    const int nb = out_size / 16;      // 512 graphs

    const int* esrc = ei;
    const int* edst = ei + e;

    char* p = (char*)d_ws;
    auto carve = [&](size_t bytes) {
        char* r = p;
        p += (bytes + 255) & ~(size_t)255;
        return r;
    };
    float*  dinv = (float*)carve((size_t)n * 4);
    __half* bufT = (__half*)carve((size_t)n * 64 * 2);        // fp16 t (6.4 MB)
    float*  bufH = (float*)carve((size_t)n * 64 * 4);         // fp32 h (12.8 MB)
    int2*   recs = (int2*) carve((size_t)NBK * CAPB * 8);     // 12.58 MB, LIVE all layers
    int*    fctr = (int*)  carve(NBK * 4);

    dim3 blk(256);
    int gBIN = (e + BINTILE - 1) / BINTILE;  // 306 tiles
    int gMM  = (n + 63) / 64;

    init_kernel<<<4, blk, 0, stream>>>(fctr);
    bin_kernel<<<gBIN, blk, 0, stream>>>(esrc, edst, fctr, recs, e, n);
    dinv_kernel<<<NBK, blk, 0, stream>>>(recs, fctr, dinv, n);

    mm_kernel<<<gMM, blk, 0, stream>>>(x, W1, dinv, bufT, n);
    agg_kernel<<<NBK, blk, 0, stream>>>(recs, fctr, bufT, dinv, b1, bufH, n);
    mm_kernel<<<gMM, blk, 0, stream>>>(bufH, W2, dinv, bufT, n);
    agg_kernel<<<NBK, blk, 0, stream>>>(recs, fctr, bufT, dinv, b2, bufH, n);
    mm_kernel<<<gMM, blk, 0, stream>>>(bufH, W3, dinv, bufT, n);
    agg_kernel<<<NBK, blk, 0, stream>>>(recs, fctr, bufT, dinv, b3, bufH, n);

    poolfinal_kernel<<<nb, blk, 0, stream>>>(bufH, batch, Wl, bl, out, n);
}

// Round 12
// 319.007 us; speedup vs baseline: 4.5864x; 4.5864x over previous
//
#include <hip/hip_runtime.h>
#include <hip/hip_fp16.h>

// ---------------------------------------------------------------------------
// GCN (3 layers) + global mean pool + linear, fp32 in/out, MI355X.
// norm = dinv[src]*dinv[dst] factors -> fold dinv into matmul output
// (t'[i] = dinv[i] * h[i] W^T); aggregation is a pure unweighted CSR sum:
//   h_next[i] = relu(dinv[i]*(t'[i] + sum_{j->i} t'[j]) + b)
// R3-R5 (counter-verified): scattered 4B GLOBAL stores/atomics cost a ~32B
//   HBM write sector each regardless of L2 residency; dense stores only.
// R9: fp16 t -> row = 128B = 1 L2 line; absmax 1.2e-4 passes.
// R11 (counter-verified): LDS-scatter agg = 80M ds_add_f32 -> 420us/layer,
//   VALUBusy 1.3% -- LDS float atomics are pipe-throughput-bound. Never
//   per-feature atomic scatter, even in LDS.
// R10/R12 lesson: match gather unroll to mean degree (25): 4grpx16lane main
//   loop engages at deg>=16 (most nodes); 8x8 needed deg>=33 (rarely) ->
//   tail-serialized, ~10us/layer slower.
// R12 = best-known recombination: R10 bin (tile 4096, reg-cached) + R10
//   fused poolfinal (zero atomics) + CSR build + R9 agg (4x16 uint2).
// ---------------------------------------------------------------------------

#define CAPB 3072
#define BINTILE 4096

__global__ __launch_bounds__(256) void init_kernel(int* __restrict__ fctr) {
    int idx = blockIdx.x * blockDim.x + threadIdx.x;
    if (idx < 512) fctr[idx] = 0;
}

// Bucket edges into 512 fine dst-ranges (fixed capacity CAPB, base=g*CAPB).
// Per 4096-edge tile: dst+bucket cached in regs; sweep1 LDS histogram; one
// global reservation per bucket; sweep2 dense 8-rec (64B) appends.
__global__ __launch_bounds__(256) void bin512_kernel(const int* __restrict__ src,
                                                     const int* __restrict__ dst,
                                                     int* __restrict__ fctr,
                                                     int2* __restrict__ recs2,
                                                     int e, int n) {
    __shared__ int lcnt[512], gbase[512];
    int tid = threadIdx.x;
    int s0  = blockIdx.x * BINTILE;
    lcnt[tid] = 0;
    lcnt[tid + 256] = 0;
    __syncthreads();
    int dv[16], bk[16];
#pragma unroll
    for (int k = 0; k < 16; ++k) {
        int i = s0 + tid + k * 256;  // coalesced
        if (i < e) {
            dv[k] = dst[i];
            bk[k] = (int)((512LL * dv[k]) / n);
            atomicAdd(&lcnt[bk[k]], 1);
        } else {
            bk[k] = -1;
        }
    }
    __syncthreads();
#pragma unroll
    for (int j = 0; j < 2; ++j) {
        int b = tid + j * 256;
        gbase[b] = b * CAPB + atomicAdd(&fctr[b], lcnt[b]);
        lcnt[b]  = 0;  // reuse as placement counter
    }
    __syncthreads();
#pragma unroll
    for (int k = 0; k < 16; ++k) {
        if (bk[k] >= 0) {
            int i = s0 + tid + k * 256;
            int p = gbase[bk[k]] + atomicAdd(&lcnt[bk[k]], 1);
            if (p < (bk[k] + 1) * CAPB) recs2[p] = make_int2(src[i], dv[k]);
        }
    }
}

// Single wave: exclusive scan of fctr[0..512) -> fbase[0..512].
__global__ __launch_bounds__(64) void scan512_kernel(const int* __restrict__ fctr,
                                                     int* __restrict__ fbase) {
    int tid = threadIdx.x;
    int carry = 0;
    for (int b0 = 0; b0 < 512; b0 += 64) {
        int v    = fctr[b0 + tid];
        int orig = v;
        for (int d = 1; d < 64; d <<= 1) {
            int t = __shfl_up(v, d, 64);
            if (tid >= d) v += t;
        }
        fbase[b0 + tid] = carry + v - orig;  // exclusive
        carry += __shfl(v, 63, 64);
    }
}

// One block per fine bucket: LDS histogram over its <=98 local nodes ->
// prefix -> counting sort into stage -> dense csr writes. Produces rp/dinv.
__global__ __launch_bounds__(256) void sortfill_kernel(const int2* __restrict__ recs2,
                                                       const int* __restrict__ fctr,
                                                       const int* __restrict__ fbase,
                                                       int* __restrict__ rp,
                                                       float* __restrict__ dinv,
                                                       int* __restrict__ csr, int n) {
    __shared__ int hist[128];
    __shared__ int lofs[129];
    __shared__ int stage[4096];
    int g   = blockIdx.x;
    int N0  = (int)(((long long)n * g + 511) / 512);
    int N1  = (int)(((long long)n * (g + 1) + 511) / 512);
    int nn  = N1 - N0;  // <= 98
    int tid = threadIdx.x;
    if (tid < 128) hist[tid] = 0;
    __syncthreads();
    const int2* my = recs2 + (size_t)g * CAPB;
    int total = min(fctr[g], CAPB);
    for (int i = tid; i < total; i += 256)
        atomicAdd(&hist[my[i].y - N0], 1);
    __syncthreads();
    if (tid == 0) {
        int acc = 0;
        for (int k = 0; k < nn; ++k) { lofs[k] = acc; acc += hist[k]; }
        lofs[nn] = acc;
    }
    __syncthreads();
    if (tid < 128) hist[tid] = 0;  // reuse as placement counters
    __syncthreads();
    int base = fbase[g];
    for (int i = tid; i < total; i += 256) {
        int2 rec = my[i];
        int  li  = rec.y - N0;
        int  pos = lofs[li] + atomicAdd(&hist[li], 1);
        stage[pos] = rec.x;  // pos < total <= CAPB < 4096
    }
    __syncthreads();
    for (int j = tid; j < total; j += 256) csr[base + j] = stage[j];
    if (tid < nn) {
        rp[N0 + tid]   = base + lofs[tid];
        int deg        = lofs[tid + 1] - lofs[tid];
        dinv[N0 + tid] = rsqrtf((float)(deg + 1));
    }
    if (g == 511 && tid == 0) rp[n] = base + total;
}

// t[i][o] = fp16( dinv[i] * sum_k h[i][k] * W[o][k] )
// 256 thr = 4 waves; 64 nodes/block. W row per lane in 16 float4 regs;
// 64 h-rows staged in LDS, read as broadcast float4. Row store = dense 128B.
__global__ __launch_bounds__(256) void mm_kernel(const float* __restrict__ h,
                                                 const float* __restrict__ W,
                                                 const float* __restrict__ dinv,
                                                 __half* __restrict__ t, int n) {
    __shared__ float hs[64 * 64];
    int tid  = threadIdx.x;
    int lane = tid & 63;
    int wave = tid >> 6;
    int base = blockIdx.x * 64;

    float4 wreg[16];
    const float4* W4 = (const float4*)(W + lane * 64);
#pragma unroll
    for (int q = 0; q < 16; ++q) wreg[q] = W4[q];

    int nrows = min(64, n - base);
    const float4* h4  = (const float4*)(h + (size_t)base * 64);
    float4*       hs4 = (float4*)hs;
    for (int idx = tid; idx < nrows * 16; idx += 256) hs4[idx] = h4[idx];
    __syncthreads();

    for (int r = wave * 16; r < wave * 16 + 16; ++r) {
        int i = base + r;
        if (i >= n) break;
        const float4* row = (const float4*)(hs + r * 64);
        float acc = 0.0f;
#pragma unroll
        for (int q = 0; q < 16; ++q) {
            float4 hv = row[q];  // wave-uniform address -> LDS broadcast
            acc += hv.x * wreg[q].x + hv.y * wreg[q].y +
                   hv.z * wreg[q].z + hv.w * wreg[q].w;
        }
        t[(size_t)i * 64 + lane] = __float2half(acc * dinv[i]);
    }
}

// One wave per node: 4 edge-groups x 16 feature-lanes (main loop engages at
// deg>=16 -- matched to mean degree 25). Each 8B (half4) gather instruction
// fetches 4 rows (each 128B = 1 L2 line); 4-deep unroll = 16 edges in
// flight; shfl_xor(16,32) cross-group reduce; grp0 dense 256B store.
__global__ __launch_bounds__(256) void agg_kernel(const __half* __restrict__ t,
                                                  const int* __restrict__ rp,
                                                  const int* __restrict__ cs,
                                                  const float* __restrict__ dinv,
                                                  const float* __restrict__ bias,
                                                  float* __restrict__ hout, int n) {
    int gw   = (blockIdx.x * blockDim.x + threadIdx.x) >> 6;
    int lane = threadIdx.x & 63;
    if (gw >= n) return;
    int i   = gw;
    int grp = lane >> 4;          // edge group 0..3
    int fo  = (lane & 15) << 2;   // feature offset (halves) 0,4,..,60
    int beg = rp[i];
    int end = rp[i + 1];

    float4 a0 = make_float4(0.f, 0.f, 0.f, 0.f);
    float4 a1 = a0, a2 = a0, a3 = a0;
    int e = beg + grp;
    for (; e + 12 < end; e += 16) {
        int s0 = cs[e];
        int s1 = cs[e + 4];
        int s2 = cs[e + 8];
        int s3 = cs[e + 12];
        uint2 u0 = *(const uint2*)(t + (size_t)s0 * 64 + fo);
        uint2 u1 = *(const uint2*)(t + (size_t)s1 * 64 + fo);
        uint2 u2 = *(const uint2*)(t + (size_t)s2 * 64 + fo);
        uint2 u3 = *(const uint2*)(t + (size_t)s3 * 64 + fo);
        float2 f;
        f = __half22float2(*(const __half2*)&u0.x); a0.x += f.x; a0.y += f.y;
        f = __half22float2(*(const __half2*)&u0.y); a0.z += f.x; a0.w += f.y;
        f = __half22float2(*(const __half2*)&u1.x); a1.x += f.x; a1.y += f.y;
        f = __half22float2(*(const __half2*)&u1.y); a1.z += f.x; a1.w += f.y;
        f = __half22float2(*(const __half2*)&u2.x); a2.x += f.x; a2.y += f.y;
        f = __half22float2(*(const __half2*)&u2.y); a2.z += f.x; a2.w += f.y;
        f = __half22float2(*(const __half2*)&u3.x); a3.x += f.x; a3.y += f.y;
        f = __half22float2(*(const __half2*)&u3.y); a3.z += f.x; a3.w += f.y;
    }
    for (; e < end; e += 4) {
        int s = cs[e];
        uint2 u = *(const uint2*)(t + (size_t)s * 64 + fo);
        float2 f;
        f = __half22float2(*(const __half2*)&u.x); a1.x += f.x; a1.y += f.y;
        f = __half22float2(*(const __half2*)&u.y); a1.z += f.x; a1.w += f.y;
    }
    float4 acc;
    acc.x = (a0.x + a1.x) + (a2.x + a3.x);
    acc.y = (a0.y + a1.y) + (a2.y + a3.y);
    acc.z = (a0.z + a1.z) + (a2.z + a3.z);
    acc.w = (a0.w + a1.w) + (a2.w + a3.w);
    acc.x += __shfl_xor(acc.x, 16, 64);
    acc.y += __shfl_xor(acc.y, 16, 64);
    acc.z += __shfl_xor(acc.z, 16, 64);
    acc.w += __shfl_xor(acc.w, 16, 64);
    acc.x += __shfl_xor(acc.x, 32, 64);
    acc.y += __shfl_xor(acc.y, 32, 64);
    acc.z += __shfl_xor(acc.z, 32, 64);
    acc.w += __shfl_xor(acc.w, 32, 64);
    if (grp == 0) {
        uint2 su = *(const uint2*)(t + (size_t)i * 64 + fo);
        float2 s01 = __half22float2(*(const __half2*)&su.x);
        float2 s23 = __half22float2(*(const __half2*)&su.y);
        float4 bv = *(const float4*)(bias + fo);
        float  dv = dinv[i];
        float4 o;
        o.x = fmaxf(fmaf(dv, acc.x + s01.x, bv.x), 0.0f);
        o.y = fmaxf(fmaf(dv, acc.y + s01.y, bv.y), 0.0f);
        o.z = fmaxf(fmaf(dv, acc.z + s23.x, bv.z), 0.0f);
        o.w = fmaxf(fmaf(dv, acc.w + s23.y, bv.w), 0.0f);
        *(float4*)(hout + (size_t)i * 64 + fo) = o;
    }
}

// Fused mean-pool + linear: one block per graph. Node range via binary
// search in sorted batch (L2-hot); register accumulate (NO atomics);
// wave0 computes mean and the 16-wide output row.
__global__ __launch_bounds__(256) void poolfinal_kernel(const float* __restrict__ h,
                                                        const int* __restrict__ batch,
                                                        const float* __restrict__ Wl,
                                                        const float* __restrict__ bl,
                                                        float* __restrict__ out,
                                                        int n) {
    __shared__ float red[4][64];
    int b    = blockIdx.x;
    int tid  = threadIdx.x;
    int lane = tid & 63;
    int w    = tid >> 6;
    int l = 0, r = n;
    while (l < r) { int m = (l + r) >> 1; if (batch[m] < b) l = m + 1; else r = m; }
    int lo = l;
    r = n;
    while (l < r) { int m = (l + r) >> 1; if (batch[m] < b + 1) l = m + 1; else r = m; }
    int hi = l;

    float acc = 0.0f;
    for (int i = lo + w; i < hi; i += 4) acc += h[(size_t)i * 64 + lane];
    red[w][lane] = acc;
    __syncthreads();
    if (w == 0) {
        float s = (red[0][lane] + red[1][lane]) + (red[2][lane] + red[3][lane]);
        float c = (float)(hi - lo);
        red[0][lane] = s / fmaxf(c, 1.0f);
    }
    __syncthreads();
    if (tid < 16) {
        float a = bl[tid];
        const float* wr = Wl + tid * 64;
#pragma unroll
        for (int k = 0; k < 64; ++k) a += red[0][k] * wr[k];
        out[b * 16 + tid] = a;
    }
}

extern "C" void kernel_launch(void* const* d_in, const int* in_sizes, int n_in,
                              void* d_out, int out_size, void* d_ws, size_t ws_size,
                              hipStream_t stream) {
    const float* x    = (const float*)d_in[0];
    const int*   ei   = (const int*)d_in[1];
    const int*   batch= (const int*)d_in[2];
    const float* W1   = (const float*)d_in[3];
    const float* b1   = (const float*)d_in[4];
    const float* W2   = (const float*)d_in[5];
    const float* b2   = (const float*)d_in[6];
    const float* W3   = (const float*)d_in[7];
    const float* b3   = (const float*)d_in[8];
    const float* Wl   = (const float*)d_in[9];
    const float* bl   = (const float*)d_in[10];
    float* out = (float*)d_out;

    const int n  = in_sizes[0] / 64;   // 50000 nodes
    const int e  = in_sizes[1] / 2;    // 1250000 edges
    const int nb = out_size / 16;      // 512 graphs

    const int* esrc = ei;
    const int* edst = ei + e;

    char* p = (char*)d_ws;
    auto carve = [&](size_t bytes) {
        char* r = p;
        p += (bytes + 255) & ~(size_t)255;
        return r;
    };
    size_t featBytes = (size_t)n * 64 * 4;     // 12.80 MB (fp32 h)
    size_t recsBytes = (size_t)512 * CAPB * 8; // 12.58 MB recs2
    size_t bufBBytes = recsBytes > featBytes ? recsBytes : featBytes;

    float*  dinv = (float*)carve((size_t)n * 4);
    int*    rp   = (int*)  carve((size_t)(n + 1) * 4);
    int*    csr  = (int*)  carve((size_t)e * 4);
    __half* bufT = (__half*)carve((size_t)n * 64 * 2);  // fp16 t (6.4 MB)
    float*  bufB = (float*)carve(bufBBytes);            // recs2, then h
    int*    fctr = (int*)  carve(512 * 4);
    int*    fbase= (int*)  carve(512 * 4);
    int2*   recs2 = (int2*)bufB;  // dead before agg1 writes bufB

    dim3 blk(256);
    int gBIN = (e + BINTILE - 1) / BINTILE;  // 4096-edge tiles -> 306 blocks

    init_kernel<<<2, blk, 0, stream>>>(fctr);
    bin512_kernel<<<gBIN, blk, 0, stream>>>(esrc, edst, fctr, recs2, e, n);
    scan512_kernel<<<1, 64, 0, stream>>>(fctr, fbase);
    sortfill_kernel<<<512, blk, 0, stream>>>(recs2, fctr, fbase, rp, dinv, csr, n);

    int gMM  = (n + 63) / 64;
    int gAGG = (n + 3) / 4;  // 4 waves/block, one node per wave

    mm_kernel<<<gMM, blk, 0, stream>>>(x, W1, dinv, bufT, n);
    agg_kernel<<<gAGG, blk, 0, stream>>>(bufT, rp, csr, dinv, b1, bufB, n);
    mm_kernel<<<gMM, blk, 0, stream>>>(bufB, W2, dinv, bufT, n);
    agg_kernel<<<gAGG, blk, 0, stream>>>(bufT, rp, csr, dinv, b2, bufB, n);
    mm_kernel<<<gMM, blk, 0, stream>>>(bufB, W3, dinv, bufT, n);
    agg_kernel<<<gAGG, blk, 0, stream>>>(bufT, rp, csr, dinv, b3, bufB, n);

    poolfinal_kernel<<<nb, blk, 0, stream>>>(bufB, batch, Wl, bl, out, n);
}